// Round 8
// baseline (80.890 us; speedup 1.0000x reference)
//
#include <hip/hip_runtime.h>

#define NUM_WIRES 4
#define NUM_LAYERS 2

// R12: ILP-2 interleave. R11 (branch/barrier/LDS-free preamble) came back
// flat (78.4) -> prologue wasn't the cost. Ledger: body marginal 13-17us vs
// 9us issue floor (VALUBusy ~74%, ~26% stall), fixed ~10-15us not explained
// by prologue/dispatch/VGPR. Theory: narrow dependency regions (trig chain
// at body start, reduction tree at end, load->first-use) leave issue gaps
// that ~3-5 effective resident waves don't cover. Fix: each thread processes
// TWO elements (b, b+batch/2; both float4-coalesced) with bodies fully
// unrolled so the scheduler interleaves two independent DAGs -> 2x stall
// cover, preamble amortized 2x, wave count halved (2048 blocks).
// Body math unchanged from the verified R8/R11 kernel.
//
// G[] layout (floats):
//  [ 0..15]  layer-0 per wire w: {A=cx*cz, B=cx*sz, C=sx*sz, D=sx*cz}
//  [16..23]  layer-1 RX per wire: {cos, sin}
//  [24..55]  layer-1 combined RZ diagonal: 16 x {dr, di}
//
// State layout: amp[i], bit3=wire0 ... bit0=wire3 (reference (B,2,2,2,2) order).

#define INV_4PI 0.07957747154594767f  // 0.5 / (2*pi): sin(0.5x) = v_sin(x * INV_4PI)

__device__ __forceinline__ float RL(float v, int lane) {
    return __int_as_float(__builtin_amdgcn_readlane(__float_as_int(v), lane));
}

__device__ __forceinline__ void cmul(float ar, float ai, float br, float bi,
                                     float& orr, float& oi) {
    orr = fmaf(ar, br, -(ai * bi));
    oi  = fmaf(ar, bi,   ai * br);
}

template <int CM, int TM>
__device__ __forceinline__ void cnot(float zr[16], float zi[16]) {
#pragma unroll
    for (int i = 0; i < 16; ++i) {
        if ((i & CM) && !(i & TM)) {
            const int j = i | TM;
            float t;
            t = zr[i]; zr[i] = zr[j]; zr[j] = t;
            t = zi[i]; zi[i] = zi[j]; zi[j] = t;
        }
    }
}

__device__ __forceinline__ float4 qsim_body(const float4 xv, const float* __restrict__ G) {
    // Layer-0: fused gate applied to each wire's RY(x)|0> = (c,s) factor.
    float fr[4][2], fi[4][2];
    {
        const float xs[4] = {xv.x, xv.y, xv.z, xv.w};
#pragma unroll
        for (int q = 0; q < 4; ++q) {
            const float r = xs[q] * INV_4PI;
            const float s = __builtin_amdgcn_sinf(r);
            const float c = __builtin_amdgcn_cosf(r);
            const float A = G[q * 4 + 0], B = G[q * 4 + 1];
            const float C = G[q * 4 + 2], D = G[q * 4 + 3];
            fr[q][0] = fmaf(A, c, C * s);      // u00r*c + u01r*s
            fi[q][0] = fmaf(-B, c, -(D * s));  // u00i*c + u01i*s
            fr[q][1] = fmaf(A, s, -(C * c));   // u10r*c + u11r*s
            fi[q][1] = fmaf(B, s, -(D * c));   // u10i*c + u11i*s
        }
    }

    // Complex outer product: z = (f0 (x) f1) (x) (f2 (x) f3)
    float mr[4], mi[4], nr[4], ni[4];
#pragma unroll
    for (int p = 0; p < 2; ++p)
#pragma unroll
        for (int q = 0; q < 2; ++q) {
            cmul(fr[0][p], fi[0][p], fr[1][q], fi[1][q], mr[p * 2 + q], mi[p * 2 + q]);
            cmul(fr[2][p], fi[2][p], fr[3][q], fi[3][q], nr[p * 2 + q], ni[p * 2 + q]);
        }
    float zr[16], zi[16];
#pragma unroll
    for (int i = 0; i < 16; ++i)
        cmul(mr[i >> 2], mi[i >> 2], nr[i & 3], ni[i & 3], zr[i], zi[i]);

    // Layer-0 CNOT ring (free register permutation)
    cnot<8, 4>(zr, zi);
    cnot<4, 2>(zr, zi);
    cnot<2, 1>(zr, zi);
    cnot<1, 8>(zr, zi);

    // Layer-1 combined RZ diagonal
#pragma unroll
    for (int i = 0; i < 16; ++i) {
        const float dr = G[24 + i * 2], dii = G[25 + i * 2];
        const float ar = zr[i], ai = zi[i];
        zr[i] = fmaf(dr, ar, -(dii * ai));
        zi[i] = fmaf(dr, ai,   dii * ar);
    }

    // Layer-1 RX per wire: new_a = c*a - i*s*b -> (c*ar + s*bi, c*ai - s*br)
#pragma unroll
    for (int q = 0; q < 4; ++q) {
        const float c = G[16 + q * 2], s = G[17 + q * 2];
        const int M = 8 >> q;
#pragma unroll
        for (int i = 0; i < 16; ++i) {
            if (!(i & M)) {
                const int j = i | M;
                const float ar = zr[i], ai = zi[i];
                const float br = zr[j], bi = zi[j];
                zr[i] = fmaf(c, ar,   s * bi);
                zi[i] = fmaf(c, ai, -(s * br));
                zr[j] = fmaf(c, br,   s * ai);
                zi[j] = fmaf(c, bi, -(s * ar));
            }
        }
    }

    // Layer-1 CNOT ring
    cnot<8, 4>(zr, zi);
    cnot<4, 2>(zr, zi);
    cnot<2, 1>(zr, zi);
    cnot<1, 8>(zr, zi);

    // Probabilities and <Z_w> via sum/difference tree
    float p[16];
#pragma unroll
    for (int i = 0; i < 16; ++i) p[i] = fmaf(zr[i], zr[i], zi[i] * zi[i]);

    float d0[8], s1[8];
#pragma unroll
    for (int k = 0; k < 8; ++k) {
        d0[k] = p[2 * k] - p[2 * k + 1];
        s1[k] = p[2 * k] + p[2 * k + 1];
    }
    const float e3 = ((d0[0] + d0[1]) + (d0[2] + d0[3])) + ((d0[4] + d0[5]) + (d0[6] + d0[7]));
    const float e2 = ((s1[0] - s1[1]) + (s1[2] - s1[3])) + ((s1[4] - s1[5]) + (s1[6] - s1[7]));
    float s2[4];
#pragma unroll
    for (int k = 0; k < 4; ++k) s2[k] = s1[2 * k] + s1[2 * k + 1];
    const float e1 = (s2[0] - s2[1]) + (s2[2] - s2[3]);
    const float e0 = (s2[0] + s2[1]) - (s2[2] + s2[3]);

    return make_float4(e0, e1, e2, e3);
}

__global__ __launch_bounds__(256) void qsim_kernel(const float* __restrict__ x,
                                                   const float* __restrict__ params,
                                                   float* __restrict__ out, int batch) {
    const int L = threadIdx.x & 63;
    const int w = L & 3;
    const int di = L & 15;

    // params (16 floats), uniform addresses -> scalarizable broadcast loads.
    const float4 P0 = reinterpret_cast<const float4*>(params)[0];  // L0 w0,w1: {z,x,z,x}
    const float4 P1 = reinterpret_cast<const float4*>(params)[1];  // L0 w2,w3
    const float4 P2 = reinterpret_cast<const float4*>(params)[2];  // L1 w0,w1
    const float4 P3 = reinterpret_cast<const float4*>(params)[3];  // L1 w2,w3

    // --- my-wire (w = L&3) layer-0 params, layer-1 RX param ---
    const float pz0 = (w == 0) ? P0.x : (w == 1) ? P0.z : (w == 2) ? P1.x : P1.z;
    const float px0 = (w == 0) ? P0.y : (w == 1) ? P0.w : (w == 2) ? P1.y : P1.w;
    const float px1 = (w == 0) ? P2.y : (w == 1) ? P2.w : (w == 2) ? P3.y : P3.w;

    // layer-0 fused consts (native trig; |0.5p|/2pi << 0.5 for N(0,1) params)
    const float rz = pz0 * INV_4PI;
    const float sz = __builtin_amdgcn_sinf(rz), cz = __builtin_amdgcn_cosf(rz);
    const float rx = px0 * INV_4PI;
    const float sx = __builtin_amdgcn_sinf(rx), cx = __builtin_amdgcn_cosf(rx);
    const float vA = cx * cz, vB = cx * sz, vC = sx * sz, vD = sx * cz;

    // layer-1 RX consts
    const float rx1 = px1 * INV_4PI;
    const float vS1 = __builtin_amdgcn_sinf(rx1), vC1 = __builtin_amdgcn_cosf(rx1);

    // --- my diag entry (di = L&15): prod over wires of (c_w + i*sg_w) ---
    float ddr, ddi;
    {
        const float z0 = P2.x * INV_4PI, z1 = P2.z * INV_4PI;
        const float z2 = P3.x * INV_4PI, z3 = P3.z * INV_4PI;
        const float c0 = __builtin_amdgcn_cosf(z0), s0 = __builtin_amdgcn_sinf(z0);
        const float c1 = __builtin_amdgcn_cosf(z1), s1 = __builtin_amdgcn_sinf(z1);
        const float c2 = __builtin_amdgcn_cosf(z2), s2 = __builtin_amdgcn_sinf(z2);
        const float c3 = __builtin_amdgcn_cosf(z3), s3 = __builtin_amdgcn_sinf(z3);
        const float g0 = (di & 8) ? s0 : -s0;  // bit (3-w'): w'=0 -> bit3
        const float g1 = (di & 4) ? s1 : -s1;
        const float g2 = (di & 2) ? s2 : -s2;
        const float g3 = (di & 1) ? s3 : -s3;
        ddr = c0; ddi = g0;
        float t;
        t = ddr * c1 - ddi * g1; ddi = fmaf(ddr, g1, ddi * c1); ddr = t;
        t = ddr * c2 - ddi * g2; ddi = fmaf(ddr, g2, ddi * c2); ddr = t;
        t = ddr * c3 - ddi * g3; ddi = fmaf(ddr, g3, ddi * c3); ddr = t;
    }

    // --- gather all 56 batch-uniform constants into SGPRs via readlane ---
    float G[56];
#pragma unroll
    for (int q = 0; q < 4; ++q) {
        G[q * 4 + 0] = RL(vA, q);
        G[q * 4 + 1] = RL(vB, q);
        G[q * 4 + 2] = RL(vC, q);
        G[q * 4 + 3] = RL(vD, q);
        G[16 + q * 2] = RL(vC1, q);
        G[17 + q * 2] = RL(vS1, q);
    }
#pragma unroll
    for (int q = 0; q < 16; ++q) {
        G[24 + q * 2] = RL(ddr, q);
        G[25 + q * 2] = RL(ddi, q);
    }

    // --- Two elements per thread: b and b + half (both coalesced) ---
    const int half = batch >> 1;
    const int b1 = blockIdx.x * 256 + threadIdx.x;
    if (b1 >= half) return;
    const int b2 = b1 + half;

    const float4 xv1 = reinterpret_cast<const float4*>(x)[b1];
    const float4 xv2 = reinterpret_cast<const float4*>(x)[b2];

    // Two independent DAGs; fully unrolled so the scheduler interleaves them.
    const float4 r1 = qsim_body(xv1, G);
    const float4 r2 = qsim_body(xv2, G);

    reinterpret_cast<float4*>(out)[b1] = r1;
    reinterpret_cast<float4*>(out)[b2] = r2;
}

extern "C" void kernel_launch(void* const* d_in, const int* in_sizes, int n_in,
                              void* d_out, int out_size, void* d_ws, size_t ws_size,
                              hipStream_t stream) {
    const float* x = (const float*)d_in[0];        // (B, 4) float32
    const float* params = (const float*)d_in[1];   // (2, 4, 2) float32
    float* out = (float*)d_out;                    // (B, 4) float32
    const int batch = in_sizes[0] / NUM_WIRES;

    const int half = (batch + 1) / 2;
    const int blocks = (half + 255) / 256;
    qsim_kernel<<<blocks, 256, 0, stream>>>(x, params, out, batch);
}

// Round 9
// 78.644 us; speedup vs baseline: 1.0286x; 1.0286x over previous
//
#include <hip/hip_runtime.h>

#define NUM_WIRES 4
#define NUM_LAYERS 2

// R13: R11 base (best, 78.45us) + load hoisting. R12's ILP-2 regressed
// (80.9: VGPR pressure cost the 8-wave occupancy tier and halved wave
// count) -> reverted. Remaining micro-theory: R11 issues the x float4 load
// AFTER the ~190-inst preamble (12 trans + 56 serial readlanes), so the
// body's first xv use eats a ~500cy VMEM latency with ~3 effective waves
// of cover. This round issues the x load (index clamped, always in-bounds)
// at instruction 0, ahead of the params loads + preamble -> whole preamble
// becomes latency cover. Store remains guarded. Math unchanged.
//
// G[] layout (floats):
//  [ 0..15]  layer-0 per wire w: {A=cx*cz, B=cx*sz, C=sx*sz, D=sx*cz}
//  [16..23]  layer-1 RX per wire: {cos, sin}
//  [24..55]  layer-1 combined RZ diagonal: 16 x {dr, di}
//
// State layout: amp[i], bit3=wire0 ... bit0=wire3 (reference (B,2,2,2,2) order).

#define INV_4PI 0.07957747154594767f  // 0.5 / (2*pi): sin(0.5x) = v_sin(x * INV_4PI)

__device__ __forceinline__ float RL(float v, int lane) {
    return __int_as_float(__builtin_amdgcn_readlane(__float_as_int(v), lane));
}

__device__ __forceinline__ void cmul(float ar, float ai, float br, float bi,
                                     float& orr, float& oi) {
    orr = fmaf(ar, br, -(ai * bi));
    oi  = fmaf(ar, bi,   ai * br);
}

template <int CM, int TM>
__device__ __forceinline__ void cnot(float zr[16], float zi[16]) {
#pragma unroll
    for (int i = 0; i < 16; ++i) {
        if ((i & CM) && !(i & TM)) {
            const int j = i | TM;
            float t;
            t = zr[i]; zr[i] = zr[j]; zr[j] = t;
            t = zi[i]; zi[i] = zi[j]; zi[j] = t;
        }
    }
}

__global__ __launch_bounds__(256) void qsim_kernel(const float* __restrict__ x,
                                                   const float* __restrict__ params,
                                                   float* __restrict__ out, int batch) {
    // --- Issue the batch-element load FIRST (clamped index: always valid).
    const int b = blockIdx.x * 256 + threadIdx.x;
    const int bc = (b < batch) ? b : 0;
    const float4 xv = reinterpret_cast<const float4*>(x)[bc];

    const int L = threadIdx.x & 63;
    const int w = L & 3;
    const int di = L & 15;

    // params (16 floats), uniform addresses -> scalarizable broadcast loads.
    const float4 P0 = reinterpret_cast<const float4*>(params)[0];  // L0 w0,w1: {z,x,z,x}
    const float4 P1 = reinterpret_cast<const float4*>(params)[1];  // L0 w2,w3
    const float4 P2 = reinterpret_cast<const float4*>(params)[2];  // L1 w0,w1
    const float4 P3 = reinterpret_cast<const float4*>(params)[3];  // L1 w2,w3

    // --- my-wire (w = L&3) layer-0 params, layer-1 RX param ---
    const float pz0 = (w == 0) ? P0.x : (w == 1) ? P0.z : (w == 2) ? P1.x : P1.z;
    const float px0 = (w == 0) ? P0.y : (w == 1) ? P0.w : (w == 2) ? P1.y : P1.w;
    const float px1 = (w == 0) ? P2.y : (w == 1) ? P2.w : (w == 2) ? P3.y : P3.w;

    // layer-0 fused consts (native trig; |0.5p|/2pi << 0.5 for N(0,1) params)
    const float rz = pz0 * INV_4PI;
    const float sz = __builtin_amdgcn_sinf(rz), cz = __builtin_amdgcn_cosf(rz);
    const float rx = px0 * INV_4PI;
    const float sx = __builtin_amdgcn_sinf(rx), cx = __builtin_amdgcn_cosf(rx);
    const float vA = cx * cz, vB = cx * sz, vC = sx * sz, vD = sx * cz;

    // layer-1 RX consts
    const float rx1 = px1 * INV_4PI;
    const float vS1 = __builtin_amdgcn_sinf(rx1), vC1 = __builtin_amdgcn_cosf(rx1);

    // --- my diag entry (di = L&15): prod over wires of (c_w + i*sg_w) ---
    float ddr, ddi;
    {
        const float z0 = P2.x * INV_4PI, z1 = P2.z * INV_4PI;
        const float z2 = P3.x * INV_4PI, z3 = P3.z * INV_4PI;
        const float c0 = __builtin_amdgcn_cosf(z0), s0 = __builtin_amdgcn_sinf(z0);
        const float c1 = __builtin_amdgcn_cosf(z1), s1 = __builtin_amdgcn_sinf(z1);
        const float c2 = __builtin_amdgcn_cosf(z2), s2 = __builtin_amdgcn_sinf(z2);
        const float c3 = __builtin_amdgcn_cosf(z3), s3 = __builtin_amdgcn_sinf(z3);
        const float g0 = (di & 8) ? s0 : -s0;  // bit (3-w'): w'=0 -> bit3
        const float g1 = (di & 4) ? s1 : -s1;
        const float g2 = (di & 2) ? s2 : -s2;
        const float g3 = (di & 1) ? s3 : -s3;
        ddr = c0; ddi = g0;
        float t;
        t = ddr * c1 - ddi * g1; ddi = fmaf(ddr, g1, ddi * c1); ddr = t;
        t = ddr * c2 - ddi * g2; ddi = fmaf(ddr, g2, ddi * c2); ddr = t;
        t = ddr * c3 - ddi * g3; ddi = fmaf(ddr, g3, ddi * c3); ddr = t;
    }

    // --- gather all 56 batch-uniform constants into SGPRs via readlane ---
    float G[56];
#pragma unroll
    for (int q = 0; q < 4; ++q) {
        G[q * 4 + 0] = RL(vA, q);
        G[q * 4 + 1] = RL(vB, q);
        G[q * 4 + 2] = RL(vC, q);
        G[q * 4 + 3] = RL(vD, q);
        G[16 + q * 2] = RL(vC1, q);
        G[17 + q * 2] = RL(vS1, q);
    }
#pragma unroll
    for (int q = 0; q < 16; ++q) {
        G[24 + q * 2] = RL(ddr, q);
        G[25 + q * 2] = RL(ddi, q);
    }

    // Layer-0: fused gate applied to each wire's RY(x)|0> = (c,s) factor.
    float fr[4][2], fi[4][2];
    {
        const float xs[4] = {xv.x, xv.y, xv.z, xv.w};
#pragma unroll
        for (int q = 0; q < 4; ++q) {
            const float r = xs[q] * INV_4PI;
            const float s = __builtin_amdgcn_sinf(r);
            const float c = __builtin_amdgcn_cosf(r);
            const float A = G[q * 4 + 0], B = G[q * 4 + 1];
            const float C = G[q * 4 + 2], D = G[q * 4 + 3];
            fr[q][0] = fmaf(A, c, C * s);      // u00r*c + u01r*s
            fi[q][0] = fmaf(-B, c, -(D * s));  // u00i*c + u01i*s
            fr[q][1] = fmaf(A, s, -(C * c));   // u10r*c + u11r*s
            fi[q][1] = fmaf(B, s, -(D * c));   // u10i*c + u11i*s
        }
    }

    // Complex outer product: z = (f0 (x) f1) (x) (f2 (x) f3)
    float mr[4], mi[4], nr[4], ni[4];
#pragma unroll
    for (int p = 0; p < 2; ++p)
#pragma unroll
        for (int q = 0; q < 2; ++q) {
            cmul(fr[0][p], fi[0][p], fr[1][q], fi[1][q], mr[p * 2 + q], mi[p * 2 + q]);
            cmul(fr[2][p], fi[2][p], fr[3][q], fi[3][q], nr[p * 2 + q], ni[p * 2 + q]);
        }
    float zr[16], zi[16];
#pragma unroll
    for (int i = 0; i < 16; ++i)
        cmul(mr[i >> 2], mi[i >> 2], nr[i & 3], ni[i & 3], zr[i], zi[i]);

    // Layer-0 CNOT ring (free register permutation)
    cnot<8, 4>(zr, zi);
    cnot<4, 2>(zr, zi);
    cnot<2, 1>(zr, zi);
    cnot<1, 8>(zr, zi);

    // Layer-1 combined RZ diagonal
#pragma unroll
    for (int i = 0; i < 16; ++i) {
        const float dr = G[24 + i * 2], dii = G[25 + i * 2];
        const float ar = zr[i], ai = zi[i];
        zr[i] = fmaf(dr, ar, -(dii * ai));
        zi[i] = fmaf(dr, ai,   dii * ar);
    }

    // Layer-1 RX per wire: new_a = c*a - i*s*b -> (c*ar + s*bi, c*ai - s*br)
#pragma unroll
    for (int q = 0; q < 4; ++q) {
        const float c = G[16 + q * 2], s = G[17 + q * 2];
        const int M = 8 >> q;
#pragma unroll
        for (int i = 0; i < 16; ++i) {
            if (!(i & M)) {
                const int j = i | M;
                const float ar = zr[i], ai = zi[i];
                const float br = zr[j], bi = zi[j];
                zr[i] = fmaf(c, ar,   s * bi);
                zi[i] = fmaf(c, ai, -(s * br));
                zr[j] = fmaf(c, br,   s * ai);
                zi[j] = fmaf(c, bi, -(s * ar));
            }
        }
    }

    // Layer-1 CNOT ring
    cnot<8, 4>(zr, zi);
    cnot<4, 2>(zr, zi);
    cnot<2, 1>(zr, zi);
    cnot<1, 8>(zr, zi);

    // Probabilities and <Z_w> via sum/difference tree
    float p[16];
#pragma unroll
    for (int i = 0; i < 16; ++i) p[i] = fmaf(zr[i], zr[i], zi[i] * zi[i]);

    float d0[8], s1[8];
#pragma unroll
    for (int k = 0; k < 8; ++k) {
        d0[k] = p[2 * k] - p[2 * k + 1];
        s1[k] = p[2 * k] + p[2 * k + 1];
    }
    const float e3 = ((d0[0] + d0[1]) + (d0[2] + d0[3])) + ((d0[4] + d0[5]) + (d0[6] + d0[7]));
    const float e2 = ((s1[0] - s1[1]) + (s1[2] - s1[3])) + ((s1[4] - s1[5]) + (s1[6] - s1[7]));
    float s2[4];
#pragma unroll
    for (int k = 0; k < 4; ++k) s2[k] = s1[2 * k] + s1[2 * k + 1];
    const float e1 = (s2[0] - s2[1]) + (s2[2] - s2[3]);
    const float e0 = (s2[0] + s2[1]) - (s2[2] + s2[3]);

    if (b < batch)
        reinterpret_cast<float4*>(out)[b] = make_float4(e0, e1, e2, e3);
}

extern "C" void kernel_launch(void* const* d_in, const int* in_sizes, int n_in,
                              void* d_out, int out_size, void* d_ws, size_t ws_size,
                              hipStream_t stream) {
    const float* x = (const float*)d_in[0];        // (B, 4) float32
    const float* params = (const float*)d_in[1];   // (2, 4, 2) float32
    float* out = (float*)d_out;                    // (B, 4) float32
    const int batch = in_sizes[0] / NUM_WIRES;

    const int blocks = (batch + 255) / 256;
    qsim_kernel<<<blocks, 256, 0, stream>>>(x, params, out, batch);
}